// Round 5
// baseline (473.307 us; speedup 1.0000x reference)
//
#include <hip/hip_runtime.h>
#include <hip/hip_bf16.h>

#define BB 16
#define SS 2048
#define DD 64

typedef __attribute__((ext_vector_type(8)))  unsigned short ushort8;
typedef __attribute__((ext_vector_type(8)))  __bf16 bf16x8;
typedef __attribute__((ext_vector_type(16))) float f32x16;

static __device__ __forceinline__ unsigned short f2bf(float x) {
    return __builtin_bit_cast(unsigned short, __float2bfloat16(x));
}
static __device__ __forceinline__ unsigned pk2(float a, float b) {
    return (unsigned)f2bf(a) | ((unsigned)f2bf(b) << 16);
}

union F4 { float4 v; float a[4]; };

// bf16 MFMA attention: S^T = K*Q^T (32x32x16 tiles), P built in-register via
// shfl_xor(32) from the C-layout, O^T = V^T * P^T. No max-subtraction:
// logits bounded, masked -> p = 1.0f exactly (exp(1e-9)==1.0f).
// Mask is int32 {0,1} per element (proven: r3 byte-cast failed, r4 word path
// passed); any nonzero word == true also covers a fp32 {0,1.0f} encoding.
__global__ __launch_bounds__(256, 2)
void sdpa_mfma_kernel(const float* __restrict__ Q, const float* __restrict__ K,
                      const float* __restrict__ V, const unsigned int* __restrict__ M,
                      float* __restrict__ O) {
    // LDS carve: Qs 8K | Ks 8K | Vs 8K | Ms 4.5K  (swizzled 16B-granule tiles)
    __shared__ __align__(16) char smem[29184];
    char* Qs = smem;
    char* Ks = smem + 8192;
    char* Vs = smem + 16384;
    char* Ms = smem + 24576;
    float* red  = (float*)(smem + 8192);    // epilogue: reuse Ks+Vs (16 KB)
    float* denx = (float*)(smem + 24576);   // epilogue: reuse Ms

    const int t    = threadIdx.x;
    const int lane = t & 63;
    const int l31  = lane & 31;
    const int half = lane >> 5;
    const int w    = t >> 6;
    const int qs   = w & 1;    // q-subtile (rows 32*qs..32*qs+31 of block tile)
    const int kh   = w >> 1;   // k-split half (k chunk 32*kh of each 64-tile)
    const int b    = blockIdx.y;
    const int q0   = blockIdx.x * 64;

    const float* Qg = Q + ((size_t)b * SS + q0) * DD;
    const float* Kg = K + (size_t)b * SS * DD;
    const float* Vg = V + (size_t)b * SS * DD;
    const unsigned int* Mg = M + (size_t)b * SS * SS + (size_t)q0 * SS;

    const int sr = t >> 2;     // staging row 0..63
    const int sc = t & 3;      // staging col group 0..3 (16 elems each)

    // ---- stage Q tile (pre-scaled by 1/temperature), swizzled bf16 ----
    {
        F4 f0, f1, f2, f3;
        const float* src = Qg + sr * DD + sc * 16;
        f0.v = *(const float4*)(src);
        f1.v = *(const float4*)(src + 4);
        f2.v = *(const float4*)(src + 8);
        f3.v = *(const float4*)(src + 12);
        ushort8 u0, u1;
        #pragma unroll
        for (int e = 0; e < 4; e++) {
            u0[e]     = f2bf(f0.a[e] * 0.125f);
            u0[e + 4] = f2bf(f1.a[e] * 0.125f);
            u1[e]     = f2bf(f2.a[e] * 0.125f);
            u1[e + 4] = f2bf(f3.a[e] * 0.125f);
        }
        *(ushort8*)(Qs + sr * 128 + (((sc * 2)     ^ (sr & 7)) * 16)) = u0;
        *(ushort8*)(Qs + sr * 128 + (((sc * 2 + 1) ^ (sr & 7)) * 16)) = u1;
    }
    __syncthreads();

    // ---- preload Q fragments (B operand), kept in registers all loop ----
    const int qrow = 32 * qs + l31;
    ushort8 bq[4];
    #pragma unroll
    for (int dc = 0; dc < 4; dc++)
        bq[dc] = *(const ushort8*)(Qs + qrow * 128 + (((2 * dc + half) ^ (qrow & 7)) * 16));

    f32x16 On0, On1;           // O^T accumulators: d 0..31 / 32..63
    #pragma unroll
    for (int i = 0; i < 16; i++) { On0[i] = 0.f; On1[i] = 0.f; }
    float den_acc = 0.f;

    const int krow = 32 * kh + l31;
    const int d0v  = (t & 15) * 4;
    const int kkb  = (t >> 4) * 2;

    for (int kt = 0; kt < SS / 64; ++kt) {
        // ---- stage K tile (swizzled bf16) ----
        {
            F4 f0, f1, f2, f3;
            const float* src = Kg + (size_t)(kt * 64 + sr) * DD + sc * 16;
            f0.v = *(const float4*)(src);
            f1.v = *(const float4*)(src + 4);
            f2.v = *(const float4*)(src + 8);
            f3.v = *(const float4*)(src + 12);
            ushort8 u0, u1;
            #pragma unroll
            for (int e = 0; e < 4; e++) {
                u0[e]     = f2bf(f0.a[e]);
                u0[e + 4] = f2bf(f1.a[e]);
                u1[e]     = f2bf(f2.a[e]);
                u1[e + 4] = f2bf(f3.a[e]);
            }
            *(ushort8*)(Ks + sr * 128 + (((sc * 2)     ^ (sr & 7)) * 16)) = u0;
            *(ushort8*)(Ks + sr * 128 + (((sc * 2 + 1) ^ (sr & 7)) * 16)) = u1;
        }
        // ---- stage V transposed: Vs[d][k] (swizzled bf16) ----
        {
            #pragma unroll
            for (int it2 = 0; it2 < 2; it2++) {
                const int kk = kkb + 32 * it2;
                F4 va, vb;
                va.v = *(const float4*)(Vg + (size_t)(kt * 64 + kk)     * DD + d0v);
                vb.v = *(const float4*)(Vg + (size_t)(kt * 64 + kk + 1) * DD + d0v);
                #pragma unroll
                for (int e = 0; e < 4; e++) {
                    const int d = d0v + e;
                    *(unsigned*)(Vs + d * 128 + (((kk >> 3) ^ (d & 7)) * 16) + (kk & 7) * 2)
                        = pk2(va.a[e], vb.a[e]);
                }
            }
        }
        // ---- stage mask tile: int32 words -> bytes, Ms[q][k] pitch 72 ----
        {
            const unsigned int* Mw = Mg + (size_t)sr * SS + kt * 64 + sc * 16;
            unsigned wd[4];
            #pragma unroll
            for (int g = 0; g < 4; g++) {
                const uint4 u = *(const uint4*)(Mw + 4 * g);
                wd[g] = (u.x ? 1u : 0u) | (u.y ? 0x100u : 0u) |
                        (u.z ? 0x10000u : 0u) | (u.w ? 0x1000000u : 0u);
            }
            *(uint2*)(Ms + sr * 72 + sc * 16)     = make_uint2(wd[0], wd[1]);
            *(uint2*)(Ms + sr * 72 + sc * 16 + 8) = make_uint2(wd[2], wd[3]);
        }
        __syncthreads();

        // ---- QK^T: S^T tile [32k x 32q] ----
        f32x16 S;
        #pragma unroll
        for (int i = 0; i < 16; i++) S[i] = 0.f;
        #pragma unroll
        for (int dc = 0; dc < 4; dc++) {
            bf16x8 ak = __builtin_bit_cast(bf16x8,
                *(const ushort8*)(Ks + krow * 128 + (((2 * dc + half) ^ (krow & 7)) * 16)));
            S = __builtin_amdgcn_mfma_f32_32x32x16_bf16(
                    ak, __builtin_bit_cast(bf16x8, bq[dc]), S, 0, 0, 0);
        }

        // ---- mask + exp + denominator (C row = (reg&3)+8*(reg>>2)+4*half) ----
        float p[16];
        #pragma unroll
        for (int g = 0; g < 4; g++) {
            const unsigned mw = *(const unsigned*)(Ms + qrow * 72 + 32 * kh + 8 * g + 4 * half);
            #pragma unroll
            for (int e = 0; e < 4; e++) {
                const float ev = __expf(S[4 * g + e]);
                const float pv = ((mw >> (8 * e)) & 0xffu) ? 1.0f : ev;
                p[4 * g + e] = pv;
                den_acc += pv;
            }
        }

        // ---- P·V: build B-operand frags via shfl_xor(32), 2 ksubs ----
        #pragma unroll
        for (int s2 = 0; s2 < 2; s2++) {
            const unsigned o0 = pk2(p[8 * s2 + 0], p[8 * s2 + 1]);
            const unsigned o1 = pk2(p[8 * s2 + 2], p[8 * s2 + 3]);
            const unsigned o2 = pk2(p[8 * s2 + 4], p[8 * s2 + 5]);
            const unsigned o3 = pk2(p[8 * s2 + 6], p[8 * s2 + 7]);
            const unsigned s0 = half ? o0 : o2;   // half0 sends its rows 16s2+8..11
            const unsigned s1 = half ? o1 : o3;   // half1 sends its rows 16s2+4..7
            const unsigned r0 = (unsigned)__shfl_xor((int)s0, 32, 64);
            const unsigned r1 = (unsigned)__shfl_xor((int)s1, 32, 64);
            uint4 bu;
            bu.x = half ? r0 : o0;
            bu.y = half ? r1 : o1;
            bu.z = half ? o2 : r0;
            bu.w = half ? o3 : r1;
            const bf16x8 bp = __builtin_bit_cast(bf16x8, bu);
            #pragma unroll
            for (int dc = 0; dc < 2; dc++) {
                const int vrow = 32 * dc + l31;
                bf16x8 av = __builtin_bit_cast(bf16x8,
                    *(const ushort8*)(Vs + vrow * 128 +
                        (((4 * kh + 2 * s2 + half) ^ (vrow & 7)) * 16)));
                if (dc == 0) On0 = __builtin_amdgcn_mfma_f32_32x32x16_bf16(av, bp, On0, 0, 0, 0);
                else         On1 = __builtin_amdgcn_mfma_f32_32x32x16_bf16(av, bp, On1, 0, 0, 0);
            }
        }
        __syncthreads();
    }

    // ---- epilogue: combine lane halves, then the two k-split waves ----
    const float den_tot = den_acc + __shfl_xor(den_acc, 32, 64);

    __syncthreads();
    if (kh == 1) {
        #pragma unroll
        for (int dc = 0; dc < 2; dc++)
            #pragma unroll
            for (int g = 0; g < 4; g++) {
                const f32x16& Oc = dc ? On1 : On0;
                float4 st;
                st.x = Oc[4 * g + 0]; st.y = Oc[4 * g + 1];
                st.z = Oc[4 * g + 2]; st.w = Oc[4 * g + 3];
                *(float4*)((char*)red + qs * 8192 + (dc * 4 + g) * 1024 + lane * 16) = st;
            }
        if (lane < 32) denx[qs * 32 + l31] = den_tot;
    }
    __syncthreads();
    if (kh == 0) {
        const float inv = 1.0f / (den_tot + denx[qs * 32 + l31]);
        float* Og = O + ((size_t)b * SS + q0 + qrow) * DD;
        #pragma unroll
        for (int dc = 0; dc < 2; dc++)
            #pragma unroll
            for (int g = 0; g < 4; g++) {
                const float4 pr = *(const float4*)((char*)red + qs * 8192 + (dc * 4 + g) * 1024 + lane * 16);
                const f32x16& Oc = dc ? On1 : On0;
                float4 st;
                st.x = (Oc[4 * g + 0] + pr.x) * inv;
                st.y = (Oc[4 * g + 1] + pr.y) * inv;
                st.z = (Oc[4 * g + 2] + pr.z) * inv;
                st.w = (Oc[4 * g + 3] + pr.w) * inv;
                // d = e + 8*g + 4*half + 32*dc  (C-row formula)
                *(float4*)(Og + 32 * dc + 8 * g + 4 * half) = st;
            }
    }
}

extern "C" void kernel_launch(void* const* d_in, const int* in_sizes, int n_in,
                              void* d_out, int out_size, void* d_ws, size_t ws_size,
                              hipStream_t stream) {
    const float* q = (const float*)d_in[0];
    const float* k = (const float*)d_in[1];
    const float* v = (const float*)d_in[2];
    const unsigned int* m = (const unsigned int*)d_in[3];
    float* out = (float*)d_out;

    dim3 grid(SS / 64, BB);   // 32 x 16 = 512 blocks -> 2 per CU
    sdpa_mfma_kernel<<<grid, 256, 0, stream>>>(q, k, v, m, out);
}

// Round 6
// 394.426 us; speedup vs baseline: 1.2000x; 1.2000x over previous
//
#include <hip/hip_runtime.h>
#include <hip/hip_bf16.h>

#define BB 16
#define SS 2048
#define DD 64

typedef __attribute__((ext_vector_type(8)))  unsigned short ushort8;
typedef __attribute__((ext_vector_type(8)))  __bf16 bf16x8;
typedef __attribute__((ext_vector_type(16))) float f32x16;

static __device__ __forceinline__ unsigned short f2bf(float x) {
    return __builtin_bit_cast(unsigned short, __float2bfloat16(x));
}
static __device__ __forceinline__ unsigned pk2(float a, float b) {
    return (unsigned)f2bf(a) | ((unsigned)f2bf(b) << 16);
}
union F4 { float4 v; float a[4]; };

// bf16 MFMA attention, 32x32x16 tiles. S^T = K*Q^T; P built in-register via
// shfl_xor(32) from the C-layout (proven r5); O^T = V^T * P^T.
// q-tile 32 -> 1024 blocks = 4 blocks/CU (latency hiding was the r5 limiter).
// k-tile 128/iter, 4-way k-split across waves. Mask = int32 words (proven r4).
// No max-subtraction: logits bounded; masked -> p = 1.0f exactly.
__global__ __launch_bounds__(256, 4)
void sdpa_mfma_kernel(const float* __restrict__ Q, const float* __restrict__ K,
                      const float* __restrict__ V, const unsigned int* __restrict__ M,
                      float* __restrict__ O) {
    // Ks 16K (128k x 64d bf16, pitch 128, 8-granule XOR swizzle)
    // Vs 16K (V^T: 64d x 128k bf16, pitch 256, 16-granule XOR swizzle)
    // Ms 4.25K (32q x 128k mask bytes, pitch 136); Qs overlaps Ms (pre-loop only)
    __shared__ __align__(16) char smem[37120];
    char* Ks = smem;
    char* Vs = smem + 16384;
    char* Ms = smem + 32768;
    char* Qs = smem + 32768;
    float* red  = (float*)smem;              // epilogue partials (24 KB < 32 KB)
    float* denx = (float*)(smem + 32768);    // epilogue den exchange

    const int t    = threadIdx.x;
    const int lane = t & 63;
    const int l31  = lane & 31;
    const int half = lane >> 5;
    const int kh   = t >> 6;          // wave = k-chunk 32*kh of the 128-tile
    const int b    = blockIdx.y;
    const int q0   = blockIdx.x * 32;

    const float* Kg = K + (size_t)b * SS * DD;
    const float* Vg = V + (size_t)b * SS * DD;
    const unsigned int* Mg = M + (size_t)b * SS * SS + (size_t)q0 * SS;

    // ---- stage Q (pre-scaled by 1/temperature), swizzled bf16 ----
    {
        const int sr = t >> 3, sc = t & 7;
        const float* src = Q + ((size_t)b * SS + q0 + sr) * DD + sc * 8;
        F4 f0, f1; f0.v = *(const float4*)src; f1.v = *(const float4*)(src + 4);
        ushort8 u;
        #pragma unroll
        for (int e = 0; e < 4; e++) {
            u[e]     = f2bf(f0.a[e] * 0.125f);
            u[e + 4] = f2bf(f1.a[e] * 0.125f);
        }
        *(ushort8*)(Qs + sr * 128 + ((sc ^ (sr & 7)) * 16)) = u;
    }
    __syncthreads();

    // ---- preload Q fragments (B operand); all 4 waves share the q-tile ----
    const int qrow = l31;
    bf16x8 bq[4];
    #pragma unroll
    for (int dc = 0; dc < 4; dc++)
        bq[dc] = __builtin_bit_cast(bf16x8, *(const ushort8*)(
            Qs + qrow * 128 + (((2 * dc + half) ^ (qrow & 7)) * 16)));
    __syncthreads();   // Qs region becomes Ms from here on

    f32x16 On0, On1;
    #pragma unroll
    for (int i = 0; i < 16; i++) { On0[i] = 0.f; On1[i] = 0.f; }
    float den_acc = 0.f;

    const int krow = 32 * kh + l31;
    const int d0v  = (t & 15) * 4;    // V staging: d columns
    const int kkb  = (t >> 4) * 4;    // V staging: k row quad base

    for (int kt = 0; kt < SS / 128; ++kt) {
        // ---- stage K tile 128x64: flat coalesced float4 pairs -> b128 ----
        #pragma unroll
        for (int j = 0; j < 4; j++) {
            const int idx = 2 * t + 512 * j;        // float4 index in tile
            const int row = idx >> 4;
            const int g   = (idx & 15) >> 1;        // 16B granule
            const float* src = Kg + (size_t)(kt * 128) * DD + (size_t)idx * 4;
            F4 fa, fb; fa.v = *(const float4*)src; fb.v = *(const float4*)(src + 4);
            ushort8 u;
            #pragma unroll
            for (int e = 0; e < 4; e++) { u[e] = f2bf(fa.a[e]); u[e + 4] = f2bf(fb.a[e]); }
            *(ushort8*)(Ks + row * 128 + ((g ^ (row & 7)) * 16)) = u;
        }
        // ---- stage V transposed: Vs[d][k], b64 writes ----
        #pragma unroll
        for (int it2 = 0; it2 < 2; it2++) {
            const int kk = kkb + 64 * it2;
            const float* src = Vg + (size_t)(kt * 128 + kk) * DD + d0v;
            F4 r0, r1, r2, r3;
            r0.v = *(const float4*)(src);
            r1.v = *(const float4*)(src + DD);
            r2.v = *(const float4*)(src + 2 * DD);
            r3.v = *(const float4*)(src + 3 * DD);
            #pragma unroll
            for (int e = 0; e < 4; e++) {
                const int d = d0v + e;
                const uint2 wv = make_uint2(pk2(r0.a[e], r1.a[e]), pk2(r2.a[e], r3.a[e]));
                *(uint2*)(Vs + d * 256 + (((kk >> 3) ^ (d & 15)) * 16) + (kk & 7) * 2) = wv;
            }
        }
        // ---- stage mask tile: int32 words -> bytes, pitch 136 ----
        {
            const int sr = t >> 3, sc = t & 7;
            const unsigned int* Mw = Mg + (size_t)sr * SS + kt * 128 + sc * 16;
            unsigned wd[4];
            #pragma unroll
            for (int g = 0; g < 4; g++) {
                const uint4 u = *(const uint4*)(Mw + 4 * g);
                wd[g] = (u.x ? 1u : 0u) | (u.y ? 0x100u : 0u) |
                        (u.z ? 0x10000u : 0u) | (u.w ? 0x1000000u : 0u);
            }
            *(uint2*)(Ms + sr * 136 + sc * 16)     = make_uint2(wd[0], wd[1]);
            *(uint2*)(Ms + sr * 136 + sc * 16 + 8) = make_uint2(wd[2], wd[3]);
        }
        __syncthreads();

        // ---- QK^T: S^T tile [32k x 32q] for this wave's k-chunk ----
        f32x16 S;
        #pragma unroll
        for (int i = 0; i < 16; i++) S[i] = 0.f;
        #pragma unroll
        for (int dc = 0; dc < 4; dc++) {
            bf16x8 ak = __builtin_bit_cast(bf16x8, *(const ushort8*)(
                Ks + krow * 128 + (((2 * dc + half) ^ (krow & 7)) * 16)));
            S = __builtin_amdgcn_mfma_f32_32x32x16_bf16(ak, bq[dc], S, 0, 0, 0);
        }

        // ---- mask + exp + denominator (C row = e + 8g + 4half) ----
        float p[16];
        #pragma unroll
        for (int g = 0; g < 4; g++) {
            const unsigned mw = *(const unsigned*)(Ms + qrow * 136 + 32 * kh + 8 * g + 4 * half);
            #pragma unroll
            for (int e = 0; e < 4; e++) {
                const float ev = __expf(S[4 * g + e]);
                const float pv = ((mw >> (8 * e)) & 0xffu) ? 1.0f : ev;
                p[4 * g + e] = pv;
                den_acc += pv;
            }
        }

        // ---- P·V: B-operand frags via shfl_xor(32) (proven r5), 2 ksubs ----
        #pragma unroll
        for (int s2 = 0; s2 < 2; s2++) {
            const unsigned o0 = pk2(p[8 * s2 + 0], p[8 * s2 + 1]);
            const unsigned o1 = pk2(p[8 * s2 + 2], p[8 * s2 + 3]);
            const unsigned o2 = pk2(p[8 * s2 + 4], p[8 * s2 + 5]);
            const unsigned o3 = pk2(p[8 * s2 + 6], p[8 * s2 + 7]);
            const unsigned s0 = half ? o0 : o2;
            const unsigned s1 = half ? o1 : o3;
            const unsigned r0 = (unsigned)__shfl_xor((int)s0, 32, 64);
            const unsigned r1 = (unsigned)__shfl_xor((int)s1, 32, 64);
            uint4 bu;
            bu.x = half ? r0 : o0;
            bu.y = half ? r1 : o1;
            bu.z = half ? o2 : r0;
            bu.w = half ? o3 : r1;
            const bf16x8 bp = __builtin_bit_cast(bf16x8, bu);
            #pragma unroll
            for (int dc = 0; dc < 2; dc++) {
                const int vrow = 32 * dc + l31;
                bf16x8 av = __builtin_bit_cast(bf16x8, *(const ushort8*)(
                    Vs + vrow * 256 + (((4 * kh + 2 * s2 + half) ^ (vrow & 15)) * 16)));
                if (dc == 0) On0 = __builtin_amdgcn_mfma_f32_32x32x16_bf16(av, bp, On0, 0, 0, 0);
                else         On1 = __builtin_amdgcn_mfma_f32_32x32x16_bf16(av, bp, On1, 0, 0, 0);
            }
        }
        __syncthreads();
    }

    // ---- epilogue: lane halves, then 4-way k-split reduction via LDS ----
    const float den_tot = den_acc + __shfl_xor(den_acc, 32, 64);

    __syncthreads();
    if (kh != 0) {
        #pragma unroll
        for (int dc = 0; dc < 2; dc++)
            #pragma unroll
            for (int g = 0; g < 4; g++) {
                const f32x16& Oc = dc ? On1 : On0;
                float4 st;
                st.x = Oc[4 * g + 0]; st.y = Oc[4 * g + 1];
                st.z = Oc[4 * g + 2]; st.w = Oc[4 * g + 3];
                *(float4*)((char*)red + (kh - 1) * 8192 + (dc * 4 + g) * 1024 + lane * 16) = st;
            }
        if (lane < 32) denx[kh * 32 + l31] = den_tot;
    }
    __syncthreads();
    if (kh == 0) {
        const float inv = 1.0f / (den_tot + denx[32 + l31] + denx[64 + l31] + denx[96 + l31]);
        float* Og = O + ((size_t)b * SS + q0 + qrow) * DD;
        #pragma unroll
        for (int dc = 0; dc < 2; dc++)
            #pragma unroll
            for (int g = 0; g < 4; g++) {
                const f32x16& Oc = dc ? On1 : On0;
                float4 st;
                st.x = Oc[4 * g + 0]; st.y = Oc[4 * g + 1];
                st.z = Oc[4 * g + 2]; st.w = Oc[4 * g + 3];
                #pragma unroll
                for (int w2 = 0; w2 < 3; w2++) {
                    const float4 pr = *(const float4*)((char*)red + w2 * 8192 +
                                                       (dc * 4 + g) * 1024 + lane * 16);
                    st.x += pr.x; st.y += pr.y; st.z += pr.z; st.w += pr.w;
                }
                st.x *= inv; st.y *= inv; st.z *= inv; st.w *= inv;
                // d = e + 8g + 4half + 32dc  (C-row formula)
                *(float4*)(Og + 32 * dc + 8 * g + 4 * half) = st;
            }
    }
}

extern "C" void kernel_launch(void* const* d_in, const int* in_sizes, int n_in,
                              void* d_out, int out_size, void* d_ws, size_t ws_size,
                              hipStream_t stream) {
    const float* q = (const float*)d_in[0];
    const float* k = (const float*)d_in[1];
    const float* v = (const float*)d_in[2];
    const unsigned int* m = (const unsigned int*)d_in[3];
    float* out = (float*)d_out;

    dim3 grid(SS / 32, BB);   // 64 x 16 = 1024 blocks -> 4 per CU
    sdpa_mfma_kernel<<<grid, 256, 0, stream>>>(q, k, v, m, out);
}